// Round 3
// baseline (226.698 us; speedup 1.0000x reference)
//
#include <hip/hip_runtime.h>

// Problem constants (fixed by reference: B=64, T=1024, D=256)
constexpr int Bn  = 64;
constexpr int Tn  = 1024;
constexpr int Dn  = 256;
constexpr int TPB = 256;

__device__ __forceinline__ float dot4(const float4& a, const float4& b) {
    return a.x * b.x + a.y * b.y + a.z * b.z + a.w * b.w;
}

// ---------------- Pass A: per-(i,t) norms + aligned-cos terms ----------------
// grid = Bn * (Tn/32) = 2048 blocks; block = 4 waves; wave = 8 consecutive t's
// of one row i. 16 independent float4 loads/thread, zero mid-kernel barriers.
__global__ __launch_bounds__(TPB)
void cmfm_norms(const float* __restrict__ fv, const float* __restrict__ fa,
                const int* __restrict__ labels,
                float* __restrict__ rv_ws, float* __restrict__ ra_ws,
                float* __restrict__ acc) {
    __shared__ float wred[3][4];
    const int tid  = threadIdx.x;
    const int lane = tid & 63;
    const int wv   = tid >> 6;
    const int i    = blockIdx.x >> 5;    // row 0..63 (block-uniform)
    const int tb   = blockIdx.x & 31;    // 32-t chunk
    const int tt   = lane >> 3;          // t offset within wave 0..7
    const int d8   = lane & 7;           // d-part 0..7 (8 float4 each)
    const int t    = tb * 32 + wv * 8 + tt;

    const float4* __restrict__ fv4 = reinterpret_cast<const float4*>(fv);
    const float4* __restrict__ fa4 = reinterpret_cast<const float4*>(fa);
    const size_t base = ((size_t)i * Tn + t) * (Dn / 4);

    float4 v4[8], a4[8];
    #pragma unroll
    for (int k = 0; k < 8; ++k) v4[k] = fv4[base + d8 + 8 * k];
    #pragma unroll
    for (int k = 0; k < 8; ++k) a4[k] = fa4[base + d8 + 8 * k];

    float sqv = 0.f, sqa = 0.f, dva = 0.f;
    #pragma unroll
    for (int k = 0; k < 8; ++k) {
        sqv += dot4(v4[k], v4[k]);
        sqa += dot4(a4[k], a4[k]);
        dva += dot4(v4[k], a4[k]);
    }
    // reduce across the 8 d-part lanes (in-wave)
    #pragma unroll
    for (int off = 1; off < 8; off <<= 1) {
        sqv += __shfl_xor(sqv, off);
        sqa += __shfl_xor(sqa, off);
        dva += __shfl_xor(dva, off);
    }

    float pos = 0.f, neg = 0.f, dg = 0.f;
    const int lab = labels[i];           // block-uniform, loaded once
    if (d8 == 0) {
        const float rv = 1.f / fmaxf(sqrtf(sqv), 1e-8f);
        const float ra = 1.f / fmaxf(sqrtf(sqa), 1e-8f);
        rv_ws[t * Bn + i] = rv;          // [t][i] layout -> coalesced reads in pass B
        ra_ws[t * Bn + i] = ra;
        const float cosd = dva * rv * ra;
        dg = cosd;                               // cross-term diagonal
        if (lab == 0) pos = 1.f - cosd;          // ALPHA: d_bt
        else          neg = cosd;                // BETA:  1 - d_bt
    }
    #pragma unroll
    for (int off = 1; off < 64; off <<= 1) {
        pos += __shfl_xor(pos, off);
        neg += __shfl_xor(neg, off);
        dg  += __shfl_xor(dg,  off);
    }
    if (lane == 0) { wred[0][wv] = pos; wred[1][wv] = neg; wred[2][wv] = dg; }
    __syncthreads();
    if (tid == 0) {
        atomicAdd(&acc[0], wred[0][0] + wred[0][1] + wred[0][2] + wred[0][3]);
        atomicAdd(&acc[1], wred[1][0] + wred[1][1] + wred[1][2] + wred[1][3]);
        atomicAdd(&acc[3], wred[2][0] + wred[2][1] + wred[2][2] + wred[2][3]);
    }
}

// ---------------- Pass B: factorized cross term ----------------
//   Sigma_{i!=j,t,d} vn_i an_j = Sigma_{t,d} (Sigma_i rv_i v_i)(Sigma_j ra_j a_j) - diag
// block per t (1024 blocks); wave w sums 16 rows; combine wave partials in LDS.
__global__ __launch_bounds__(TPB)
void cmfm_cross(const float* __restrict__ fv, const float* __restrict__ fa,
                const float* __restrict__ rv_ws, const float* __restrict__ ra_ws,
                float* __restrict__ acc) {
    __shared__ float rvsL[Bn];
    __shared__ float rasL[Bn];
    __shared__ __align__(16) float svL[4][Dn];
    __shared__ __align__(16) float saL[4][Dn];
    __shared__ float wred[4];

    const int tid  = threadIdx.x;
    const int lane = tid & 63;
    const int wv   = tid >> 6;
    const int t    = blockIdx.x;

    if (tid < Bn)          rvsL[tid]      = rv_ws[t * Bn + tid];
    else if (tid < 2 * Bn) rasL[tid - Bn] = ra_ws[t * Bn + tid - Bn];
    __syncthreads();

    const float4* __restrict__ fv4 = reinterpret_cast<const float4*>(fv);
    const float4* __restrict__ fa4 = reinterpret_cast<const float4*>(fa);

    float4 sv = {0.f, 0.f, 0.f, 0.f}, sa = {0.f, 0.f, 0.f, 0.f};
    const int i0 = wv * 16;
    #pragma unroll
    for (int k = 0; k < 16; ++k) {
        const int i = i0 + k;
        const size_t idx = ((size_t)i * Tn + t) * (Dn / 4) + lane;  // 1KB/instr coalesced
        const float4 v = fv4[idx];
        const float4 a = fa4[idx];
        const float rv = rvsL[i];   // wave-uniform LDS broadcast
        const float ra = rasL[i];
        sv.x = fmaf(rv, v.x, sv.x); sv.y = fmaf(rv, v.y, sv.y);
        sv.z = fmaf(rv, v.z, sv.z); sv.w = fmaf(rv, v.w, sv.w);
        sa.x = fmaf(ra, a.x, sa.x); sa.y = fmaf(ra, a.y, sa.y);
        sa.z = fmaf(ra, a.z, sa.z); sa.w = fmaf(ra, a.w, sa.w);
    }
    *reinterpret_cast<float4*>(&svL[wv][lane * 4]) = sv;
    *reinterpret_cast<float4*>(&saL[wv][lane * 4]) = sa;
    __syncthreads();

    const float svd = svL[0][tid] + svL[1][tid] + svL[2][tid] + svL[3][tid];
    const float sad = saL[0][tid] + saL[1][tid] + saL[2][tid] + saL[3][tid];
    float dotp = svd * sad;
    #pragma unroll
    for (int off = 1; off < 64; off <<= 1) dotp += __shfl_xor(dotp, off);
    if (lane == 0) wred[wv] = dotp;
    __syncthreads();
    if (tid == 0) atomicAdd(&acc[2], wred[0] + wred[1] + wred[2] + wred[3]);
}

// ---------------- finalize ----------------
__global__ void cmfm_final(const int* __restrict__ labels, const float* __restrict__ acc,
                           float* __restrict__ out) {
    if (threadIdx.x == 0) {
        int npos = 0;
        for (int i = 0; i < Bn; ++i) npos += (labels[i] == 0);
        const float pos_sum  = acc[0];
        const float neg_sum  = acc[1];
        const float dot_sum  = acc[2];   // Sigma_t Sigma_d (Sigma_i vn)(Sigma_j an)
        const float diag_sum = acc[3];   // Sigma_{i,t} cos_it
        const float cross_sum = dot_sum - diag_sum;

        const float cnt_pos = (float)npos * (float)Tn;
        const float cnt_neg = (float)(Bn - npos) * (float)Tn + (float)Bn * (float)(Bn - 1);

        float loss = 0.f;
        if (npos > 0) loss += 2.0f * pos_sum / cnt_pos;                       // ALPHA
        loss += (2.0f * neg_sum + 1.0f * cross_sum / (float)Tn) / cnt_neg;    // BETA, GAMMA
        out[0] = loss;
    }
}

extern "C" void kernel_launch(void* const* d_in, const int* in_sizes, int n_in,
                              void* d_out, int out_size, void* d_ws, size_t ws_size,
                              hipStream_t stream) {
    const float* fv     = (const float*)d_in[0];
    const float* fa     = (const float*)d_in[1];
    const int*   labels = (const int*)d_in[2];

    float* rv_ws = (float*)d_ws;                  // [Tn][Bn] = 256 KB
    float* ra_ws = rv_ws + (size_t)Tn * Bn;       // [Tn][Bn] = 256 KB
    float* acc   = ra_ws + (size_t)Tn * Bn;       // [0]=pos [1]=neg [2]=dot [3]=diag
    float* out   = (float*)d_out;

    hipMemsetAsync(acc, 0, 4 * sizeof(float), stream);
    cmfm_norms<<<Bn * (Tn / 32), TPB, 0, stream>>>(fv, fa, labels, rv_ws, ra_ws, acc);
    cmfm_cross<<<Tn, TPB, 0, stream>>>(fv, fa, rv_ws, ra_ws, acc);
    cmfm_final<<<1, 64, 0, stream>>>(labels, acc, out);
}

// Round 4
// 196.824 us; speedup vs baseline: 1.1518x; 1.1518x over previous
//
#include <hip/hip_runtime.h>

// Problem constants (fixed by reference: B=64, T=1024, D=256)
constexpr int Bn  = 64;
constexpr int Tn  = 1024;
constexpr int Dn  = 256;
constexpr int TPB = 256;   // 4 waves

__device__ __forceinline__ float dot4(const float4& a, const float4& b) {
    return a.x * b.x + a.y * b.y + a.z * b.z + a.w * b.w;
}

// ---------------- Fused single pass ----------------
// Factorized cross term:
//   Sigma_{i!=j,t,d} vn_i an_j = Sigma_t [ (Sigma_i rv_i v_i) . (Sigma_j ra_j a_j) - Sigma_i cos_it ]
// Block = one t. Wave w handles i = w*16..w*16+15. lane = d-part, so ONE wave
// instruction loads a full contiguous 1KB (i,t) row (the empirically-fast
// pattern from R3's cmfm_cross). Row norms via 64-lane xor-shuffle reduce,
// rv/ra applied immediately to the running column sums. One barrier per block.
__global__ __launch_bounds__(TPB)
void cmfm_fused(const float* __restrict__ fv, const float* __restrict__ fa,
                const int* __restrict__ labels, float* __restrict__ acc) {
    __shared__ __align__(16) float svL[4][Dn];   // per-wave partial column sums
    __shared__ __align__(16) float saL[4][Dn];
    __shared__ float wred[4][4];                 // [quantity][wave]

    const int tid  = threadIdx.x;
    const int lane = tid & 63;
    const int wv   = tid >> 6;
    const int t    = blockIdx.x;

    const float4* __restrict__ fv4 = reinterpret_cast<const float4*>(fv);
    const float4* __restrict__ fa4 = reinterpret_cast<const float4*>(fa);

    float4 sv = {0.f, 0.f, 0.f, 0.f}, sa = {0.f, 0.f, 0.f, 0.f};
    float pos = 0.f, neg = 0.f, dg = 0.f;

    const int i0 = wv * 16;
    #pragma unroll
    for (int k = 0; k < 16; ++k) {
        const int i = i0 + k;
        const size_t idx = ((size_t)i * Tn + t) * (Dn / 4) + lane;  // contiguous 1KB/wave-instr
        const float4 v = fv4[idx];
        const float4 a = fa4[idx];

        float sqv = dot4(v, v), sqa = dot4(a, a), dva = dot4(v, a);
        #pragma unroll
        for (int off = 1; off < 64; off <<= 1) {
            sqv += __shfl_xor(sqv, off);
            sqa += __shfl_xor(sqa, off);
            dva += __shfl_xor(dva, off);
        }
        // all 64 lanes now hold identical row totals
        const float rv = 1.f / fmaxf(sqrtf(sqv), 1e-8f);
        const float ra = 1.f / fmaxf(sqrtf(sqa), 1e-8f);

        sv.x = fmaf(rv, v.x, sv.x); sv.y = fmaf(rv, v.y, sv.y);
        sv.z = fmaf(rv, v.z, sv.z); sv.w = fmaf(rv, v.w, sv.w);
        sa.x = fmaf(ra, a.x, sa.x); sa.y = fmaf(ra, a.y, sa.y);
        sa.z = fmaf(ra, a.z, sa.z); sa.w = fmaf(ra, a.w, sa.w);

        const float cosd = dva * rv * ra;   // lane-uniform
        dg += cosd;                         // cross diagonal
        if (labels[i] == 0) pos += 1.f - cosd;   // ALPHA: d_bt       (same addr all lanes -> broadcast)
        else                neg += cosd;         // BETA:  1 - d_bt
    }

    // pos/neg/dg are lane-uniform wave totals already (no shuffle needed).
    *reinterpret_cast<float4*>(&svL[wv][lane * 4]) = sv;
    *reinterpret_cast<float4*>(&saL[wv][lane * 4]) = sa;
    __syncthreads();

    // thread d = tid owns column d
    const float svd = svL[0][tid] + svL[1][tid] + svL[2][tid] + svL[3][tid];
    const float sad = saL[0][tid] + saL[1][tid] + saL[2][tid] + saL[3][tid];
    float dotp = svd * sad;
    #pragma unroll
    for (int off = 1; off < 64; off <<= 1) dotp += __shfl_xor(dotp, off);

    if (lane == 0) {
        wred[0][wv] = pos;
        wred[1][wv] = neg;
        wred[2][wv] = dotp;
        wred[3][wv] = dg;
    }
    __syncthreads();
    if (tid == 0) {
        atomicAdd(&acc[0], wred[0][0] + wred[0][1] + wred[0][2] + wred[0][3]);
        atomicAdd(&acc[1], wred[1][0] + wred[1][1] + wred[1][2] + wred[1][3]);
        atomicAdd(&acc[2], wred[2][0] + wred[2][1] + wred[2][2] + wred[2][3]);
        atomicAdd(&acc[3], wred[3][0] + wred[3][1] + wred[3][2] + wred[3][3]);
    }
}

// ---------------- finalize ----------------
__global__ void cmfm_final(const int* __restrict__ labels, const float* __restrict__ acc,
                           float* __restrict__ out) {
    if (threadIdx.x == 0) {
        int npos = 0;
        for (int i = 0; i < Bn; ++i) npos += (labels[i] == 0);
        const float pos_sum  = acc[0];
        const float neg_sum  = acc[1];
        const float dot_sum  = acc[2];   // Sigma_t (Sigma_i vn).(Sigma_j an)
        const float diag_sum = acc[3];   // Sigma_{i,t} cos_it
        const float cross_sum = dot_sum - diag_sum;

        const float cnt_pos = (float)npos * (float)Tn;
        const float cnt_neg = (float)(Bn - npos) * (float)Tn + (float)Bn * (float)(Bn - 1);

        float loss = 0.f;
        if (npos > 0) loss += 2.0f * pos_sum / cnt_pos;                       // ALPHA
        loss += (2.0f * neg_sum + 1.0f * cross_sum / (float)Tn) / cnt_neg;    // BETA, GAMMA
        out[0] = loss;
    }
}

extern "C" void kernel_launch(void* const* d_in, const int* in_sizes, int n_in,
                              void* d_out, int out_size, void* d_ws, size_t ws_size,
                              hipStream_t stream) {
    const float* fv     = (const float*)d_in[0];
    const float* fa     = (const float*)d_in[1];
    const int*   labels = (const int*)d_in[2];
    float* acc = (float*)d_ws;   // [0]=pos [1]=neg [2]=dot [3]=diag
    float* out = (float*)d_out;

    hipMemsetAsync(acc, 0, 4 * sizeof(float), stream);
    cmfm_fused<<<Tn, TPB, 0, stream>>>(fv, fa, labels, acc);
    cmfm_final<<<1, 64, 0, stream>>>(labels, acc, out);
}

// Round 5
// 190.359 us; speedup vs baseline: 1.1909x; 1.0340x over previous
//
#include <hip/hip_runtime.h>

// Problem constants (fixed by reference: B=64, T=1024, D=256)
constexpr int Bn  = 64;
constexpr int Tn  = 1024;
constexpr int Dn  = 256;
constexpr int TPB = 256;   // 4 waves

__device__ __forceinline__ float dot4(const float4& a, const float4& b) {
    return a.x * b.x + a.y * b.y + a.z * b.z + a.w * b.w;
}

// ---------------- Fused single pass ----------------
// Factorized cross term:
//   Sigma_{i!=j,t,d} vn_i an_j = Sigma_t [ (Sigma_i rv_i v_i).(Sigma_j ra_j a_j) - Sigma_i cos_it ]
// Block = one t. Each 16-LANE GROUP owns one row per outer iter (lane = d-part,
// 4 float4s of the 256-float row). Row-norm reduce = 4-step xor butterfly that
// reduces FOUR rows per wave at once (3 DS/row vs R4's 18). 8 independent b128
// loads batched per iter; interior otherwise pure FMA (the empirically-fast
// R3-cross regime). One barrier + LDS combine per block.
__global__ __launch_bounds__(TPB, 4)
void cmfm_fused(const float* __restrict__ fv, const float* __restrict__ fa,
                const int* __restrict__ labels, float* __restrict__ acc) {
    __shared__ int labL[Bn];
    __shared__ __align__(16) float4 svL[16][Dn / 4];   // [subset][d4]
    __shared__ __align__(16) float4 saL[16][Dn / 4];
    __shared__ float wred[3][4];                       // [pos/neg/dg][wave]

    const int tid  = threadIdx.x;
    const int lane = tid & 63;
    const int wv   = tid >> 6;
    const int g    = lane >> 4;    // 16-lane group 0..3
    const int dp   = lane & 15;    // d-part within group
    const int t    = blockIdx.x;

    if (tid < Bn) labL[tid] = labels[tid];
    __syncthreads();

    const float4* __restrict__ fv4 = reinterpret_cast<const float4*>(fv);
    const float4* __restrict__ fa4 = reinterpret_cast<const float4*>(fa);

    float4 sv[4] = {}, sa[4] = {};       // per-lane column-sum partials (d4 = dp+16k)
    float pos = 0.f, neg = 0.f, dg = 0.f;

    #pragma unroll
    for (int o = 0; o < 4; ++o) {
        const int row = o * 16 + wv * 4 + g;
        const size_t base = ((size_t)row * Tn + t) * (Dn / 4);

        // 8 independent b128 loads, all in flight before any dependent math
        float4 v4[4], a4[4];
        #pragma unroll
        for (int k = 0; k < 4; ++k) v4[k] = fv4[base + dp + 16 * k];
        #pragma unroll
        for (int k = 0; k < 4; ++k) a4[k] = fa4[base + dp + 16 * k];

        float sqv = 0.f, sqa = 0.f, dva = 0.f;
        #pragma unroll
        for (int k = 0; k < 4; ++k) {
            sqv += dot4(v4[k], v4[k]);
            sqa += dot4(a4[k], a4[k]);
            dva += dot4(v4[k], a4[k]);
        }
        // 4-step butterfly within the 16-lane group: reduces all 4 rows of the
        // wave in the same instructions.
        #pragma unroll
        for (int off = 1; off < 16; off <<= 1) {
            sqv += __shfl_xor(sqv, off);
            sqa += __shfl_xor(sqa, off);
            dva += __shfl_xor(dva, off);
        }
        const float rv = 1.f / fmaxf(sqrtf(sqv), 1e-8f);
        const float ra = 1.f / fmaxf(sqrtf(sqa), 1e-8f);

        #pragma unroll
        for (int k = 0; k < 4; ++k) {
            sv[k].x = fmaf(rv, v4[k].x, sv[k].x); sv[k].y = fmaf(rv, v4[k].y, sv[k].y);
            sv[k].z = fmaf(rv, v4[k].z, sv[k].z); sv[k].w = fmaf(rv, v4[k].w, sv[k].w);
            sa[k].x = fmaf(ra, a4[k].x, sa[k].x); sa[k].y = fmaf(ra, a4[k].y, sa[k].y);
            sa[k].z = fmaf(ra, a4[k].z, sa[k].z); sa[k].w = fmaf(ra, a4[k].w, sa[k].w);
        }
        const float cosd = dva * rv * ra;         // uniform within group (x16 multiplicity)
        dg += cosd;
        if (labL[row] == 0) pos += 1.f - cosd;    // ALPHA: d_bt
        else                neg += cosd;          // BETA:  1 - d_bt
    }

    // stash per-subset column partials (subset = wave*4 + group)
    const int sub = wv * 4 + g;
    #pragma unroll
    for (int k = 0; k < 4; ++k) {
        svL[sub][dp + 16 * k] = sv[k];
        saL[sub][dp + 16 * k] = sa[k];
    }

    // wave-reduce the scalar terms (once per block, not per row)
    #pragma unroll
    for (int off = 1; off < 64; off <<= 1) {
        pos += __shfl_xor(pos, off);
        neg += __shfl_xor(neg, off);
        dg  += __shfl_xor(dg,  off);
    }
    if (lane == 0) { wred[0][wv] = pos; wred[1][wv] = neg; wred[2][wv] = dg; }
    __syncthreads();

    // endgame on wave 0: full column sums -> dot -> one atomic
    if (tid < Dn / 4) {
        float4 SV = {0.f, 0.f, 0.f, 0.f}, SA = {0.f, 0.f, 0.f, 0.f};
        #pragma unroll
        for (int s = 0; s < 16; ++s) {
            const float4 x = svL[s][tid];
            const float4 y = saL[s][tid];
            SV.x += x.x; SV.y += x.y; SV.z += x.z; SV.w += x.w;
            SA.x += y.x; SA.y += y.y; SA.z += y.z; SA.w += y.w;
        }
        float dotp = dot4(SV, SA);
        #pragma unroll
        for (int off = 1; off < 64; off <<= 1) dotp += __shfl_xor(dotp, off);
        if (tid == 0) {
            const float inv16 = 1.0f / 16.0f;   // undo 16-lane multiplicity
            atomicAdd(&acc[0], (wred[0][0] + wred[0][1] + wred[0][2] + wred[0][3]) * inv16);
            atomicAdd(&acc[1], (wred[1][0] + wred[1][1] + wred[1][2] + wred[1][3]) * inv16);
            atomicAdd(&acc[3], (wred[2][0] + wred[2][1] + wred[2][2] + wred[2][3]) * inv16);
            atomicAdd(&acc[2], dotp);
        }
    }
}

// ---------------- finalize ----------------
__global__ void cmfm_final(const int* __restrict__ labels, const float* __restrict__ acc,
                           float* __restrict__ out) {
    if (threadIdx.x == 0) {
        int npos = 0;
        for (int i = 0; i < Bn; ++i) npos += (labels[i] == 0);
        const float pos_sum  = acc[0];
        const float neg_sum  = acc[1];
        const float dot_sum  = acc[2];   // Sigma_t (Sigma_i vn).(Sigma_j an)
        const float diag_sum = acc[3];   // Sigma_{i,t} cos_it
        const float cross_sum = dot_sum - diag_sum;

        const float cnt_pos = (float)npos * (float)Tn;
        const float cnt_neg = (float)(Bn - npos) * (float)Tn + (float)Bn * (float)(Bn - 1);

        float loss = 0.f;
        if (npos > 0) loss += 2.0f * pos_sum / cnt_pos;                       // ALPHA
        loss += (2.0f * neg_sum + 1.0f * cross_sum / (float)Tn) / cnt_neg;    // BETA, GAMMA
        out[0] = loss;
    }
}

extern "C" void kernel_launch(void* const* d_in, const int* in_sizes, int n_in,
                              void* d_out, int out_size, void* d_ws, size_t ws_size,
                              hipStream_t stream) {
    const float* fv     = (const float*)d_in[0];
    const float* fa     = (const float*)d_in[1];
    const int*   labels = (const int*)d_in[2];
    float* acc = (float*)d_ws;   // [0]=pos [1]=neg [2]=dot [3]=diag
    float* out = (float*)d_out;

    hipMemsetAsync(acc, 0, 4 * sizeof(float), stream);
    cmfm_fused<<<Tn, TPB, 0, stream>>>(fv, fa, labels, acc);
    cmfm_final<<<1, 64, 0, stream>>>(labels, acc, out);
}

// Round 6
// 176.675 us; speedup vs baseline: 1.2831x; 1.0775x over previous
//
#include <hip/hip_runtime.h>

// Problem constants (fixed by reference: B=64, T=1024, D=256)
constexpr int Bn  = 64;
constexpr int Tn  = 1024;
constexpr int Dn  = 256;
constexpr int TPB = 256;   // 4 waves
constexpr int RPW = 16;    // rows per wave
constexpr int PP  = 65;    // transpose-buffer pitch: bank = (65r+c)%32 = (r+c)%32 -> conflict-free

__device__ __forceinline__ float dot4(const float4& a, const float4& b) {
    return a.x * b.x + a.y * b.y + a.z * b.z + a.w * b.w;
}

// ---------------- Fused single pass, fully-batched dependencies ----------------
// Factorized cross term:
//   Sigma_{i!=j,t,d} vn_i an_j = Sigma_t [ (Sigma_i rv_i v_i).(Sigma_j ra_j a_j) - Sigma_i cos_it ]
// Block = one t. Wave w holds rows w*16..w*16+15 ENTIRELY in registers
// (lane = d-part, one wave-instr = contiguous 1KB row). The load loop has no
// serializing deps (R3-cross regime); row-norm reduction is ONE batched LDS
// transpose (pitch 65, conflict-free) instead of per-row shuffle chains; rv/ra
// are then applied to the still-live registers.
__global__ __launch_bounds__(TPB, 2)
void cmfm_fused(const float* __restrict__ fv, const float* __restrict__ fa,
                const int* __restrict__ labels, float* __restrict__ acc) {
    union SMem {
        float P[3][Bn][PP];                                   // 49.9 KB transpose buffer
        struct { float4 sv[4][Dn / 4]; float4 sa[4][Dn / 4]; } eg;  // 8 KB endgame (P dead by then)
    };
    __shared__ SMem sm;
    __shared__ float S[3][Bn];
    __shared__ float rvL[Bn], raL[Bn];
    __shared__ float wredL[4];

    const int tid  = threadIdx.x;
    const int lane = tid & 63;
    const int wv   = tid >> 6;
    const int t    = blockIdx.x;

    // prefetch label early (in flight during the load loop)
    const int lab = (tid < Bn) ? labels[tid] : 0;

    const float4* __restrict__ fv4 = reinterpret_cast<const float4*>(fv);
    const float4* __restrict__ fa4 = reinterpret_cast<const float4*>(fa);

    // ---- phase 1: 32 independent contiguous loads, kept live in registers ----
    float4 v4[RPW], a4[RPW];
    #pragma unroll
    for (int k = 0; k < RPW; ++k) {
        const int r = wv * RPW + k;
        const size_t idx = ((size_t)r * Tn + t) * (Dn / 4) + lane;
        v4[k] = fv4[idx];
        a4[k] = fa4[idx];
    }
    // per-lane partials -> LDS transpose buffer (independent consumers, rolling vmcnt)
    #pragma unroll
    for (int k = 0; k < RPW; ++k) {
        const int r = wv * RPW + k;
        sm.P[0][r][lane] = dot4(v4[k], v4[k]);
        sm.P[1][r][lane] = dot4(a4[k], a4[k]);
        sm.P[2][r][lane] = dot4(v4[k], a4[k]);
    }
    __syncthreads();                                   // B1

    // ---- phase 2: batched row reduction (192 threads, conflict-free reads) ----
    if (tid < 3 * Bn) {
        const int q   = tid >> 6;
        const int row = tid & 63;
        float s0 = 0.f, s1 = 0.f, s2 = 0.f, s3 = 0.f;
        #pragma unroll
        for (int c = 0; c < 64; c += 4) {
            s0 += sm.P[q][row][c + 0];
            s1 += sm.P[q][row][c + 1];
            s2 += sm.P[q][row][c + 2];
            s3 += sm.P[q][row][c + 3];
        }
        S[q][row] = (s0 + s1) + (s2 + s3);
    }
    __syncthreads();                                   // B2

    // ---- phase 3: row scalars + scalar loss terms (wave 0 only) ----
    if (tid < Bn) {
        const float rv = 1.f / fmaxf(sqrtf(S[0][tid]), 1e-8f);
        const float ra = 1.f / fmaxf(sqrtf(S[1][tid]), 1e-8f);
        rvL[tid] = rv;
        raL[tid] = ra;
        const float cosd = S[2][tid] * rv * ra;
        float pos = 0.f, neg = 0.f, dg = cosd;
        if (lab == 0) pos = 1.f - cosd;                // ALPHA: d_bt
        else          neg = cosd;                      // BETA:  1 - d_bt
        #pragma unroll
        for (int off = 1; off < 64; off <<= 1) {       // once per block, wave 0
            pos += __shfl_xor(pos, off);
            neg += __shfl_xor(neg, off);
            dg  += __shfl_xor(dg,  off);
        }
        if (tid == 0) {
            atomicAdd(&acc[0], pos);
            atomicAdd(&acc[1], neg);
            atomicAdd(&acc[3], dg);
        }
    }
    __syncthreads();                                   // B3

    // ---- phase 4: apply rv/ra to held registers -> per-lane column sums ----
    float4 sv = {0.f, 0.f, 0.f, 0.f}, sa = {0.f, 0.f, 0.f, 0.f};
    #pragma unroll
    for (int k = 0; k < RPW; ++k) {
        const int r = wv * RPW + k;
        const float rv = rvL[r];                       // wave-uniform LDS broadcast
        const float ra = raL[r];
        sv.x = fmaf(rv, v4[k].x, sv.x); sv.y = fmaf(rv, v4[k].y, sv.y);
        sv.z = fmaf(rv, v4[k].z, sv.z); sv.w = fmaf(rv, v4[k].w, sv.w);
        sa.x = fmaf(ra, a4[k].x, sa.x); sa.y = fmaf(ra, a4[k].y, sa.y);
        sa.z = fmaf(ra, a4[k].z, sa.z); sa.w = fmaf(ra, a4[k].w, sa.w);
    }
    sm.eg.sv[wv][lane] = sv;                           // overlays P (dead after B2)
    sm.eg.sa[wv][lane] = sa;
    __syncthreads();                                   // B4

    // ---- phase 5: column combine + factorized dot + one atomic ----
    {
        const float* svf0 = reinterpret_cast<const float*>(sm.eg.sv[0]);
        const float* svf1 = reinterpret_cast<const float*>(sm.eg.sv[1]);
        const float* svf2 = reinterpret_cast<const float*>(sm.eg.sv[2]);
        const float* svf3 = reinterpret_cast<const float*>(sm.eg.sv[3]);
        const float* saf0 = reinterpret_cast<const float*>(sm.eg.sa[0]);
        const float* saf1 = reinterpret_cast<const float*>(sm.eg.sa[1]);
        const float* saf2 = reinterpret_cast<const float*>(sm.eg.sa[2]);
        const float* saf3 = reinterpret_cast<const float*>(sm.eg.sa[3]);
        const float svd = svf0[tid] + svf1[tid] + svf2[tid] + svf3[tid];
        const float sad = saf0[tid] + saf1[tid] + saf2[tid] + saf3[tid];
        float dotp = svd * sad;
        #pragma unroll
        for (int off = 1; off < 64; off <<= 1) dotp += __shfl_xor(dotp, off);
        if (lane == 0) wredL[wv] = dotp;
    }
    __syncthreads();                                   // B5
    if (tid == 0)
        atomicAdd(&acc[2], wredL[0] + wredL[1] + wredL[2] + wredL[3]);
}

// ---------------- finalize ----------------
__global__ void cmfm_final(const int* __restrict__ labels, const float* __restrict__ acc,
                           float* __restrict__ out) {
    if (threadIdx.x == 0) {
        int npos = 0;
        for (int i = 0; i < Bn; ++i) npos += (labels[i] == 0);
        const float pos_sum  = acc[0];
        const float neg_sum  = acc[1];
        const float dot_sum  = acc[2];   // Sigma_t (Sigma_i vn).(Sigma_j an)
        const float diag_sum = acc[3];   // Sigma_{i,t} cos_it
        const float cross_sum = dot_sum - diag_sum;

        const float cnt_pos = (float)npos * (float)Tn;
        const float cnt_neg = (float)(Bn - npos) * (float)Tn + (float)Bn * (float)(Bn - 1);

        float loss = 0.f;
        if (npos > 0) loss += 2.0f * pos_sum / cnt_pos;                       // ALPHA
        loss += (2.0f * neg_sum + 1.0f * cross_sum / (float)Tn) / cnt_neg;    // BETA, GAMMA
        out[0] = loss;
    }
}

extern "C" void kernel_launch(void* const* d_in, const int* in_sizes, int n_in,
                              void* d_out, int out_size, void* d_ws, size_t ws_size,
                              hipStream_t stream) {
    const float* fv     = (const float*)d_in[0];
    const float* fa     = (const float*)d_in[1];
    const int*   labels = (const int*)d_in[2];
    float* acc = (float*)d_ws;   // [0]=pos [1]=neg [2]=dot [3]=diag
    float* out = (float*)d_out;

    hipMemsetAsync(acc, 0, 4 * sizeof(float), stream);
    cmfm_fused<<<Tn, TPB, 0, stream>>>(fv, fa, labels, acc);
    cmfm_final<<<1, 64, 0, stream>>>(labels, acc, out);
}